// Round 11
// baseline (692.554 us; speedup 1.0000x reference)
//
#include <hip/hip_runtime.h>
#include <hip/hip_bf16.h>
#include <cstdint>
#include <cstddef>

#define EPS_BN 1e-5f
#define LDK1 40         // LDS leading-dim stride (ushorts)
#define LDP 264         // P panel leading dim (ushorts): 64 rows f x 264 (256 co2 + pad)

typedef __attribute__((ext_vector_type(8))) __bf16 bf16x8;
typedef __attribute__((ext_vector_type(4))) float f32x4;

__device__ __forceinline__ unsigned short f2b(float f) {
    __hip_bfloat16 h = __float2bfloat16(f);
    return __builtin_bit_cast(unsigned short, h);
}
__device__ __forceinline__ unsigned int pack2(float a, float b) {
    return (unsigned int)f2b(a) | ((unsigned int)f2b(b) << 16);
}
// wait lgkmcnt(0) only (vmcnt=63, expcnt=7 untouched), then raw barrier
__device__ __forceinline__ void lgkm_barrier() {
    __builtin_amdgcn_s_waitcnt(0xC07F);
    __builtin_amdgcn_s_barrier();
}

// ---------------- prep kernels ----------------

__global__ void prep_bn_kernel(const float* __restrict__ g1, const float* __restrict__ b1,
                               const float* __restrict__ m1, const float* __restrict__ v1,
                               const float* __restrict__ g2, const float* __restrict__ b2,
                               const float* __restrict__ m2, const float* __restrict__ v2,
                               const float* __restrict__ g3, const float* __restrict__ b3,
                               const float* __restrict__ m3, const float* __restrict__ v3,
                               float* __restrict__ bias1, float* __restrict__ bias2,
                               float* __restrict__ bias3) {
    int t = blockIdx.x * 256 + threadIdx.x;
    if (t < 256) {
        float inv = g1[t] * rsqrtf(v1[t] + EPS_BN);
        bias1[t] = b1[t] - m1[t] * inv;
    } else if (t < 512) {
        int c = t - 256;
        float inv = g2[c] * rsqrtf(v2[c] + EPS_BN);
        bias2[c] = b2[c] - m2[c] * inv;
    } else if (t < 1536) {
        int c = t - 512;
        float inv = g3[c] * rsqrtf(v3[c] + EPS_BN);
        bias3[c] = b3[c] - m3[c] * inv;
    }
}

__global__ void repack_w1(const float* __restrict__ w1, const float* __restrict__ g1,
                          const float* __restrict__ v1, unsigned short* __restrict__ w1b) {
    int idx = blockIdx.x * 256 + threadIdx.x;  // < 262144
    int co = idx >> 10;
    float inv = g1[co] * rsqrtf(v1[co] + EPS_BN);
    w1b[idx] = f2b(w1[idx] * inv);
}

__global__ void repack_w2(const float* __restrict__ w2, const float* __restrict__ g2,
                          const float* __restrict__ v2, unsigned short* __restrict__ w2r) {
    int idx = blockIdx.x * 256 + threadIdx.x;  // < 589824
    int k9 = idx >> 16;
    int rem = idx & 65535;
    int co = rem >> 8;
    int ci = rem & 255;
    float inv = g2[co] * rsqrtf(v2[co] + EPS_BN);
    w2r[idx] = f2b(w2[(co * 256 + ci) * 9 + k9] * inv);
}

__global__ void repack_w3(const float* __restrict__ w3, const float* __restrict__ g3,
                          const float* __restrict__ v3, unsigned short* __restrict__ w3b) {
    int idx = blockIdx.x * 256 + threadIdx.x;  // < 262144
    int co = idx >> 8;
    float inv = g3[co] * rsqrtf(v3[co] + EPS_BN);
    w3b[idx] = f2b(w3[idx] * inv);
}

// zero only the halo cells of in2p (116 cells/image * 256 ch)
__global__ void halo_zero(unsigned short* __restrict__ in2p) {
    int idx = blockIdx.x * 256 + threadIdx.x;  // 928*256 = 64*116*32
    int cell = idx >> 5, l8 = idx & 31;
    int n = cell / 116, c = cell % 116;
    int h, w;
    if (c < 30)      { h = 0;      w = c; }
    else if (c < 60) { h = 29;     w = c - 30; }
    else if (c < 88) { h = c - 59; w = 0; }
    else             { h = c - 87; w = 29; }
    uint4 z = {0u, 0u, 0u, 0u};
    *reinterpret_cast<uint4*>(in2p + (((size_t)n * 900) + h * 30 + w) * 256 + l8 * 8) = z;
}

// ---------------- MFMA inner step (ld = LDS leading-dim stride) ----------------
// As[m][k] stride ld (m = A-tile row), Bs[n][k] stride ld (n = B-tile row).
// D: row(quad*4+reg) follows A, col(lane&15) follows B.
__device__ __forceinline__ void mfma_step(const unsigned short* As, const unsigned short* Bs,
                                          int aoff, int boff, int ld, f32x4 acc[4][4]) {
    bf16x8 a[4], b[4];
#pragma unroll
    for (int i = 0; i < 4; ++i)
        a[i] = *reinterpret_cast<const bf16x8*>(As + aoff + i * 16 * ld);
#pragma unroll
    for (int j = 0; j < 4; ++j)
        b[j] = *reinterpret_cast<const bf16x8*>(Bs + boff + j * 16 * ld);
#pragma unroll
    for (int i = 0; i < 4; ++i)
#pragma unroll
        for (int j = 0; j < 4; ++j)
            acc[i][j] = __builtin_amdgcn_mfma_f32_16x16x32_bf16(a[i], b[j], acc[i][j], 0, 0, 0);
}

// ---------------- conv1 (FUSED transpose): 1x1 1024->256, reads x NCHW directly ----------
// (unchanged from R10 — proven) grid (392), 512 threads.
__global__ __launch_bounds__(512) void conv1_kernel(const float* __restrict__ x,
                                                    const unsigned short* __restrict__ w1b,
                                                    const float* __restrict__ bias1,
                                                    unsigned short* __restrict__ in2p) {
    __shared__ unsigned short As[2][256 * LDK1];   // 40960 B
    __shared__ unsigned short Bs[2][128 * LDK1];   // 20480 B
    const int tid = threadIdx.x;
    const int f0 = blockIdx.x * 128;
    const int lane = tid & 63, wave = tid >> 6;
    const int wA = wave & 3;     // co quarter
    const int wB = wave >> 2;    // f half
    const int l15 = lane & 15, quad = lane >> 4;

    const int ar = tid >> 1, ah = (tid & 1) * 16;
    const unsigned short* aptr = w1b + (size_t)ar * 1024 + ah;
    const int awo = ar * LDK1 + ah;

    const int cp = tid >> 5, sq = tid & 31;
    const float* xb[4];
    int bwo[4];
#pragma unroll
    for (int e = 0; e < 4; ++e) {
        int f = f0 + sq + 32 * e;
        int n = f / 784, sp = f - n * 784;
        xb[e] = x + ((size_t)n * 1024 + 2 * cp) * 784 + sp;
        bwo[e] = (sq + 32 * e) * LDK1 + 2 * cp;
    }

    f32x4 acc[4][4] = {};
    const int aoff = (wA * 64 + l15) * LDK1 + quad * 8;
    const int boff = (wB * 64 + l15) * LDK1 + quad * 8;

    uint4 ra0, ra1;
    float bv0[4], bv1[4];
    ra0 = *reinterpret_cast<const uint4*>(aptr);
    ra1 = *reinterpret_cast<const uint4*>(aptr + 8);
#pragma unroll
    for (int e = 0; e < 4; ++e) { bv0[e] = xb[e][0]; bv1[e] = xb[e][784]; }

    for (int kk = 0; kk < 32; ++kk) {
        unsigned short* A = As[kk & 1];
        unsigned short* B = Bs[kk & 1];
        *reinterpret_cast<uint4*>(A + awo) = ra0;
        *reinterpret_cast<uint4*>(A + awo + 8) = ra1;
#pragma unroll
        for (int e = 0; e < 4; ++e)
            *reinterpret_cast<unsigned int*>(B + bwo[e]) = pack2(bv0[e], bv1[e]);
        if (kk < 31) {
            int ka = (kk + 1) * 32;
            ra0 = *reinterpret_cast<const uint4*>(aptr + ka);
            ra1 = *reinterpret_cast<const uint4*>(aptr + ka + 8);
            size_t kb = (size_t)(kk + 1) * 32 * 784;
#pragma unroll
            for (int e = 0; e < 4; ++e) { bv0[e] = xb[e][kb]; bv1[e] = xb[e][kb + 784]; }
        }
        lgkm_barrier();
        mfma_step(A, B, aoff, boff, LDK1, acc);
    }

#pragma unroll
    for (int j = 0; j < 4; ++j) {
        int f = f0 + wB * 64 + j * 16 + l15;
        int n = f / 784;
        int r = f - n * 784;
        int oh = r / 28, ow = r - oh * 28;
        unsigned short* dst = in2p + ((size_t)n * 900 + (oh + 1) * 30 + (ow + 1)) * 256;
#pragma unroll
        for (int i = 0; i < 4; ++i) {
            int co = wA * 64 + i * 16 + quad * 4;
            float4 bia = *reinterpret_cast<const float4*>(bias1 + co);
            f32x4 v = acc[i][j];
            ushort4 o;
            o.x = f2b(fmaxf(v.x + bia.x, 0.f));
            o.y = f2b(fmaxf(v.y + bia.y, 0.f));
            o.z = f2b(fmaxf(v.z + bia.z, 0.f));
            o.w = f2b(fmaxf(v.w + bia.w, 0.f));
            *reinterpret_cast<ushort4*>(dst + co) = o;
        }
    }
}

// ---------------- conv23 (FUSED): conv2 -> LDS panel P -> conv3; in3 never hits global ---
// Block = 64-f panel, 256 threads (4 waves, wv = wave).
// Phase A (conv2): A = weights (256 co2 rows, waves split co2), B = spatial (64 f rows,
//   shared). 72 k-steps, 1-deep reg prefetch, 2 barriers/step (proven structure).
//   Epilogue: bias2+relu -> bf16 -> P[f][co2] (ds_write_b64: D-rows = co2, 4 consecutive).
// Phase C (conv3): ZERO barriers. A-frags straight from P (ds_read_b128, stride LDP ->
//   ~2-way bank alias); B-frags per-lane from global w3b (L2-resident, 64B-coalesced per
//   16-lane group); residual x folded into acc-init per 256-co3 iter (4 iters); relu +
//   float4 store. grid (784), 256 threads. LDS peak 51200 B -> 3 blocks/CU.
__global__ __launch_bounds__(256) void conv23_kernel(const unsigned short* __restrict__ in2p,
                                                     const unsigned short* __restrict__ w2r,
                                                     const float* __restrict__ bias2,
                                                     const unsigned short* __restrict__ w3b,
                                                     const float* __restrict__ bias3,
                                                     const float* __restrict__ x,
                                                     float* __restrict__ out) {
    __shared__ unsigned short lds[25600];          // 51200 B
    unsigned short* A2w = lds;                     // [2][256*40] = 20480 ushorts
    unsigned short* B2f = lds + 20480;             // [2][ 64*40] =  5120 ushorts
    unsigned short* P   = lds;                     // [64][264] = 16896 ushorts (reused)

    const int tid = threadIdx.x;
    const int F0 = blockIdx.x * 64;
    const int lane = tid & 63, wv = tid >> 6;
    const int l15 = lane & 15, quad = lane >> 4;
    const int trow = tid >> 2, tc8 = (tid & 3) * 8;

    // spatial source cell for this thread's staged f-row (trow in 0..63)
    int cellc;
    {
        int f = F0 + trow;
        int n = f / 784;
        int r = f - n * 784;
        int oh = r / 28, ow = r - oh * 28;
        cellc = n * 900 + (oh + 1) * 30 + (ow + 1);
    }
    const unsigned short* wbase = w2r + (size_t)trow * 256 + tc8;  // +e*64*256 for rows +64e

    f32x4 acc[4][4] = {};
    const int aoffA = (wv * 64 + l15) * LDK1 + quad * 8;   // weights rows (co2)
    const int boffB = l15 * LDK1 + quad * 8;               // spatial rows (f)
    const int woA = trow * LDK1 + tc8;
    const int woB = trow * LDK1 + tc8;

    // ---- Phase A: conv2, 72 k-steps, 1-deep prefetch ----
    uint4 rW0, rW1, rW2, rW3, rS;
    {   // kn=0: k9=0, cb=0, dd=-31
        rW0 = *reinterpret_cast<const uint4*>(wbase);
        rW1 = *reinterpret_cast<const uint4*>(wbase + 64 * 256);
        rW2 = *reinterpret_cast<const uint4*>(wbase + 128 * 256);
        rW3 = *reinterpret_cast<const uint4*>(wbase + 192 * 256);
        rS  = *reinterpret_cast<const uint4*>(in2p + (size_t)(cellc - 31) * 256 + tc8);
    }
    for (int kk = 0; kk < 72; ++kk) {
        unsigned short* Aw = A2w + (kk & 1) * 10240;
        unsigned short* Bf = B2f + (kk & 1) * 2560;
        *reinterpret_cast<uint4*>(Aw + woA) = rW0;
        *reinterpret_cast<uint4*>(Aw + woA + 64 * LDK1) = rW1;
        *reinterpret_cast<uint4*>(Aw + woA + 128 * LDK1) = rW2;
        *reinterpret_cast<uint4*>(Aw + woA + 192 * LDK1) = rW3;
        *reinterpret_cast<uint4*>(Bf + woB) = rS;
        if (kk < 71) {
            int kn = kk + 1;
            int k9 = kn >> 3, cb = kn & 7;
            int kh = k9 / 3, kw = k9 - 3 * kh;
            int dd = (kh - 1) * 30 + (kw - 1);
            const unsigned short* wb = w2r + (size_t)k9 * 65536 + cb * 32 + (size_t)trow * 256 + tc8;
            rW0 = *reinterpret_cast<const uint4*>(wb);
            rW1 = *reinterpret_cast<const uint4*>(wb + 64 * 256);
            rW2 = *reinterpret_cast<const uint4*>(wb + 128 * 256);
            rW3 = *reinterpret_cast<const uint4*>(wb + 192 * 256);
            rS  = *reinterpret_cast<const uint4*>(in2p + (size_t)(cellc + dd) * 256 + cb * 32 + tc8);
        }
        lgkm_barrier();
        mfma_step(Aw, Bf, aoffA, boffB, LDK1, acc);
    }

    // ---- Phase B: acc -> P[f][co2] in LDS (bias2 + relu, bf16) ----
    __syncthreads();   // all waves done reading staging buffers
#pragma unroll
    for (int j = 0; j < 4; ++j) {
        int fcol = j * 16 + l15;                    // f row of P
#pragma unroll
        for (int i = 0; i < 4; ++i) {
            int co2b = wv * 64 + i * 16 + quad * 4; // 4 consecutive co2
            float4 bia = *reinterpret_cast<const float4*>(bias2 + co2b);
            f32x4 v = acc[i][j];
            ushort4 pk;
            pk.x = f2b(fmaxf(v.x + bia.x, 0.f));
            pk.y = f2b(fmaxf(v.y + bia.y, 0.f));
            pk.z = f2b(fmaxf(v.z + bia.z, 0.f));
            pk.w = f2b(fmaxf(v.w + bia.w, 0.f));
            *reinterpret_cast<ushort4*>(P + fcol * LDP + co2b) = pk;
        }
    }
    lgkm_barrier();    // P visible to all waves

    // ---- Phase C: conv3, 4 N-iters of 256 co3, barrier-free ----
    const int aoff3 = l15 * LDP + quad * 8;
    for (int t3 = 0; t3 < 4; ++t3) {
        int n0 = t3 * 256;
        // acc init = x residual + bias3
#pragma unroll
        for (int j = 0; j < 4; ++j) {
            int co3 = n0 + wv * 64 + j * 16 + l15;
            float b3 = bias3[co3];
#pragma unroll
            for (int i = 0; i < 4; ++i) {
                int fb = F0 + i * 16 + quad * 4;
                int n = fb / 784;
                int sp = fb - n * 784;
                float4 xr = *reinterpret_cast<const float4*>(x + ((size_t)n * 1024 + co3) * 784 + sp);
                f32x4 a;
                a.x = xr.x + b3;
                a.y = xr.y + b3;
                a.z = xr.z + b3;
                a.w = xr.w + b3;
                acc[i][j] = a;
            }
        }
        // K = 256: 8 steps; A from P (LDS), B from global w3b; no barriers
#pragma unroll
        for (int kk = 0; kk < 8; ++kk) {
            bf16x8 a[4], b[4];
#pragma unroll
            for (int i = 0; i < 4; ++i)
                a[i] = *reinterpret_cast<const bf16x8*>(P + aoff3 + i * 16 * LDP + kk * 32);
#pragma unroll
            for (int j = 0; j < 4; ++j) {
                size_t co3r = (size_t)(n0 + wv * 64 + j * 16 + l15);
                b[j] = *reinterpret_cast<const bf16x8*>(w3b + co3r * 256 + kk * 32 + quad * 8);
            }
#pragma unroll
            for (int i = 0; i < 4; ++i)
#pragma unroll
                for (int j = 0; j < 4; ++j)
                    acc[i][j] = __builtin_amdgcn_mfma_f32_16x16x32_bf16(a[i], b[j], acc[i][j], 0, 0, 0);
        }
        // epilogue: relu + float4 store
#pragma unroll
        for (int j = 0; j < 4; ++j) {
            int co3 = n0 + wv * 64 + j * 16 + l15;
#pragma unroll
            for (int i = 0; i < 4; ++i) {
                int fb = F0 + i * 16 + quad * 4;
                int n = fb / 784;
                int sp = fb - n * 784;
                size_t off = ((size_t)n * 1024 + co3) * 784 + sp;
                f32x4 v = acc[i][j];
                float4 o;
                o.x = fmaxf(v.x, 0.f);
                o.y = fmaxf(v.y, 0.f);
                o.z = fmaxf(v.z, 0.f);
                o.w = fmaxf(v.w, 0.f);
                *reinterpret_cast<float4*>(out + off) = o;
            }
        }
    }
}

// ---------------- launch ----------------

extern "C" void kernel_launch(void* const* d_in, const int* in_sizes, int n_in,
                              void* d_out, int out_size, void* d_ws, size_t ws_size,
                              hipStream_t stream) {
    const float* x  = (const float*)d_in[0];
    const float* w1 = (const float*)d_in[1];
    const float* w2 = (const float*)d_in[2];
    const float* w3 = (const float*)d_in[3];
    const float* g1 = (const float*)d_in[4];
    const float* b1 = (const float*)d_in[5];
    const float* m1 = (const float*)d_in[6];
    const float* v1 = (const float*)d_in[7];
    const float* g2 = (const float*)d_in[8];
    const float* b2 = (const float*)d_in[9];
    const float* m2 = (const float*)d_in[10];
    const float* v2 = (const float*)d_in[11];
    const float* g3 = (const float*)d_in[12];
    const float* b3 = (const float*)d_in[13];
    const float* m3 = (const float*)d_in[14];
    const float* v3 = (const float*)d_in[15];

    char* ws = (char*)d_ws;
    unsigned short* w1b  = (unsigned short*)(ws + 0);         //   524288 B
    unsigned short* w2r  = (unsigned short*)(ws + 524288);    //  1179648 B
    unsigned short* w3b  = (unsigned short*)(ws + 1703936);   //   524288 B
    float* bias1         = (float*)(ws + 2228224);            //     1024 B
    float* bias2         = (float*)(ws + 2229248);            //     1024 B
    float* bias3         = (float*)(ws + 2230272);            //     4096 B
    unsigned short* in2p = (unsigned short*)(ws + 2234368);   // 29491200 B (64*900*256 bf16)
    // total: ~31.7 MB (xt and in3 both eliminated)

    prep_bn_kernel<<<6, 256, 0, stream>>>(g1, b1, m1, v1, g2, b2, m2, v2, g3, b3, m3, v3,
                                          bias1, bias2, bias3);
    repack_w1<<<1024, 256, 0, stream>>>(w1, g1, v1, w1b);
    repack_w2<<<2304, 256, 0, stream>>>(w2, g2, v2, w2r);
    repack_w3<<<1024, 256, 0, stream>>>(w3, g3, v3, w3b);
    halo_zero<<<928, 256, 0, stream>>>(in2p);

    conv1_kernel<<<dim3(392), 512, 0, stream>>>(x, w1b, bias1, in2p);
    conv23_kernel<<<dim3(784), 256, 0, stream>>>(in2p, w2r, bias2, w3b, bias3, x,
                                                 (float*)d_out);
}

// Round 12
// 587.330 us; speedup vs baseline: 1.1792x; 1.1792x over previous
//
#include <hip/hip_runtime.h>
#include <hip/hip_bf16.h>
#include <cstdint>
#include <cstddef>

#define EPS_BN 1e-5f
#define LDK1 40         // LDS leading-dim stride (ushorts)
#define TILE1 (128 * LDK1)

typedef __attribute__((ext_vector_type(8))) __bf16 bf16x8;
typedef __attribute__((ext_vector_type(4))) float f32x4;

__device__ __forceinline__ unsigned short f2b(float f) {
    __hip_bfloat16 h = __float2bfloat16(f);
    return __builtin_bit_cast(unsigned short, h);
}
__device__ __forceinline__ unsigned int pack2(float a, float b) {
    return (unsigned int)f2b(a) | ((unsigned int)f2b(b) << 16);
}
// wait lgkmcnt(0) only (vmcnt=63, expcnt=7 untouched), then raw barrier
__device__ __forceinline__ void lgkm_barrier() {
    __builtin_amdgcn_s_waitcnt(0xC07F);
    __builtin_amdgcn_s_barrier();
}

// ---------------- prep_all: all 5 prep tasks in ONE launch (block-range dispatch) --------
// blocks [0,1024): repack w1 | [1024,3328): repack w2 | [3328,4352): repack w3 |
// [4352,5280): halo_zero     | [5280,5286): bias precompute. Tasks are independent.
__global__ __launch_bounds__(256) void prep_all(
        const float* __restrict__ w1, const float* __restrict__ w2,
        const float* __restrict__ w3,
        const float* __restrict__ g1, const float* __restrict__ b1,
        const float* __restrict__ m1, const float* __restrict__ v1,
        const float* __restrict__ g2, const float* __restrict__ b2,
        const float* __restrict__ m2, const float* __restrict__ v2,
        const float* __restrict__ g3, const float* __restrict__ b3,
        const float* __restrict__ m3, const float* __restrict__ v3,
        unsigned short* __restrict__ w1b, unsigned short* __restrict__ w2r,
        unsigned short* __restrict__ w3b,
        float* __restrict__ bias1, float* __restrict__ bias2, float* __restrict__ bias3,
        unsigned short* __restrict__ in2p) {
    const int b = blockIdx.x, t = threadIdx.x;
    if (b < 1024) {                       // repack_w1: 262144 elems
        int idx = b * 256 + t;
        int co = idx >> 10;
        float inv = g1[co] * rsqrtf(v1[co] + EPS_BN);
        w1b[idx] = f2b(w1[idx] * inv);
    } else if (b < 3328) {                // repack_w2: 589824 elems
        int idx = (b - 1024) * 256 + t;
        int k9 = idx >> 16;
        int rem = idx & 65535;
        int co = rem >> 8;
        int ci = rem & 255;
        float inv = g2[co] * rsqrtf(v2[co] + EPS_BN);
        w2r[idx] = f2b(w2[(co * 256 + ci) * 9 + k9] * inv);
    } else if (b < 4352) {                // repack_w3: 262144 elems
        int idx = (b - 3328) * 256 + t;
        int co = idx >> 8;
        float inv = g3[co] * rsqrtf(v3[co] + EPS_BN);
        w3b[idx] = f2b(w3[idx] * inv);
    } else if (b < 5280) {                // halo_zero: 928*256 items (16B each)
        int idx = (b - 4352) * 256 + t;
        int cell = idx >> 5, l8 = idx & 31;
        int n = cell / 116, c = cell % 116;
        int h, w;
        if (c < 30)      { h = 0;      w = c; }
        else if (c < 60) { h = 29;     w = c - 30; }
        else if (c < 88) { h = c - 59; w = 0; }
        else             { h = c - 87; w = 29; }
        uint4 z = {0u, 0u, 0u, 0u};
        *reinterpret_cast<uint4*>(in2p + (((size_t)n * 900) + h * 30 + w) * 256 + l8 * 8) = z;
    } else {                              // bias precompute: 1536 threads
        int tt = (b - 5280) * 256 + t;
        if (tt < 256) {
            float inv = g1[tt] * rsqrtf(v1[tt] + EPS_BN);
            bias1[tt] = b1[tt] - m1[tt] * inv;
        } else if (tt < 512) {
            int c = tt - 256;
            float inv = g2[c] * rsqrtf(v2[c] + EPS_BN);
            bias2[c] = b2[c] - m2[c] * inv;
        } else {
            int c = tt - 512;
            float inv = g3[c] * rsqrtf(v3[c] + EPS_BN);
            bias3[c] = b3[c] - m3[c] * inv;
        }
    }
}

// ---------------- MFMA inner step (ld = LDS leading-dim stride) ----------------
// As[m][k] stride ld (m = A-tile row), Bs[n][k] stride ld (n = B-tile row).
// D: row(quad*4+reg) follows A, col(lane&15) follows B.
__device__ __forceinline__ void mfma_step(const unsigned short* As, const unsigned short* Bs,
                                          int aoff, int boff, int ld, f32x4 acc[4][4]) {
    bf16x8 a[4], b[4];
#pragma unroll
    for (int i = 0; i < 4; ++i)
        a[i] = *reinterpret_cast<const bf16x8*>(As + aoff + i * 16 * ld);
#pragma unroll
    for (int j = 0; j < 4; ++j)
        b[j] = *reinterpret_cast<const bf16x8*>(Bs + boff + j * 16 * ld);
#pragma unroll
    for (int i = 0; i < 4; ++i)
#pragma unroll
        for (int j = 0; j < 4; ++j)
            acc[i][j] = __builtin_amdgcn_mfma_f32_16x16x32_bf16(a[i], b[j], acc[i][j], 0, 0, 0);
}

// ---------------- conv1 (FUSED transpose): 1x1 1024->256, reads x NCHW directly ----------
// One block = 128 f x ALL 256 co (512 threads, 8 waves: wB=f-half, wA=co-quarter), so x is
// read exactly ONCE overall. B-staging does the transpose in-flight. grid (392), 512 thr.
__global__ __launch_bounds__(512) void conv1_kernel(const float* __restrict__ x,
                                                    const unsigned short* __restrict__ w1b,
                                                    const float* __restrict__ bias1,
                                                    unsigned short* __restrict__ in2p) {
    __shared__ unsigned short As[2][256 * LDK1];   // 40960 B
    __shared__ unsigned short Bs[2][128 * LDK1];   // 20480 B
    const int tid = threadIdx.x;
    const int f0 = blockIdx.x * 128;
    const int lane = tid & 63, wave = tid >> 6;
    const int wA = wave & 3;     // co quarter
    const int wB = wave >> 2;    // f half
    const int l15 = lane & 15, quad = lane >> 4;

    const int ar = tid >> 1, ah = (tid & 1) * 16;
    const unsigned short* aptr = w1b + (size_t)ar * 1024 + ah;
    const int awo = ar * LDK1 + ah;

    const int cp = tid >> 5, sq = tid & 31;
    const float* xb[4];
    int bwo[4];
#pragma unroll
    for (int e = 0; e < 4; ++e) {
        int f = f0 + sq + 32 * e;
        int n = f / 784, sp = f - n * 784;
        xb[e] = x + ((size_t)n * 1024 + 2 * cp) * 784 + sp;
        bwo[e] = (sq + 32 * e) * LDK1 + 2 * cp;
    }

    f32x4 acc[4][4] = {};
    const int aoff = (wA * 64 + l15) * LDK1 + quad * 8;
    const int boff = (wB * 64 + l15) * LDK1 + quad * 8;

    uint4 ra0, ra1;
    float bv0[4], bv1[4];
    ra0 = *reinterpret_cast<const uint4*>(aptr);
    ra1 = *reinterpret_cast<const uint4*>(aptr + 8);
#pragma unroll
    for (int e = 0; e < 4; ++e) { bv0[e] = xb[e][0]; bv1[e] = xb[e][784]; }

    for (int kk = 0; kk < 32; ++kk) {
        unsigned short* A = As[kk & 1];
        unsigned short* B = Bs[kk & 1];
        *reinterpret_cast<uint4*>(A + awo) = ra0;
        *reinterpret_cast<uint4*>(A + awo + 8) = ra1;
#pragma unroll
        for (int e = 0; e < 4; ++e)
            *reinterpret_cast<unsigned int*>(B + bwo[e]) = pack2(bv0[e], bv1[e]);
        if (kk < 31) {
            int ka = (kk + 1) * 32;
            ra0 = *reinterpret_cast<const uint4*>(aptr + ka);
            ra1 = *reinterpret_cast<const uint4*>(aptr + ka + 8);
            size_t kb = (size_t)(kk + 1) * 32 * 784;
#pragma unroll
            for (int e = 0; e < 4; ++e) { bv0[e] = xb[e][kb]; bv1[e] = xb[e][kb + 784]; }
        }
        lgkm_barrier();
        mfma_step(A, B, aoff, boff, LDK1, acc);
    }

#pragma unroll
    for (int j = 0; j < 4; ++j) {
        int f = f0 + wB * 64 + j * 16 + l15;
        int n = f / 784;
        int r = f - n * 784;
        int oh = r / 28, ow = r - oh * 28;
        unsigned short* dst = in2p + ((size_t)n * 900 + (oh + 1) * 30 + (ow + 1)) * 256;
#pragma unroll
        for (int i = 0; i < 4; ++i) {
            int co = wA * 64 + i * 16 + quad * 4;
            float4 bia = *reinterpret_cast<const float4*>(bias1 + co);
            f32x4 v = acc[i][j];
            ushort4 o;
            o.x = f2b(fmaxf(v.x + bia.x, 0.f));
            o.y = f2b(fmaxf(v.y + bia.y, 0.f));
            o.z = f2b(fmaxf(v.z + bia.z, 0.f));
            o.w = f2b(fmaxf(v.w + bia.w, 0.f));
            *reinterpret_cast<ushort4*>(dst + co) = o;
        }
    }
}

// ---------------- conv2: 3x3 = 72 k-steps, 2-deep reg prefetch; out flat [f][256] bf16 ----
// grid (392, 2), 256 threads (R5 form — proven best variant)
__global__ __launch_bounds__(256) void conv2_kernel(const unsigned short* __restrict__ in2p,
                                                    const unsigned short* __restrict__ w2r,
                                                    const float* __restrict__ bias2,
                                                    unsigned short* __restrict__ in3) {
    __shared__ unsigned short As[2][TILE1];
    __shared__ unsigned short Bs[2][TILE1];
    const int tid = threadIdx.x;
    const int f0 = blockIdx.x * 128;
    const int m0 = blockIdx.y * 128;
    const int lane = tid & 63, wave = tid >> 6;
    const int wr = wave >> 1, wc = wave & 1;
    const int l15 = lane & 15, quad = lane >> 4;
    const int tcid = tid & 3, tcl = tid >> 2;

    // per-thread halo-center cell index for its two B rows
    int cellc[2];
#pragma unroll
    for (int p = 0; p < 2; ++p) {
        int f = f0 + p * 64 + tcl;
        int n = f / 784;
        int r = f - n * 784;
        int oh = r / 28, ow = r - oh * 28;
        cellc[p] = n * 900 + (oh + 1) * 30 + (ow + 1);
    }

    f32x4 acc[4][4] = {};
    const int aoff = (wr * 64 + l15) * LDK1 + quad * 8;
    const int boff = (wc * 64 + l15) * LDK1 + quad * 8;
    const int wo = tcl * LDK1 + tcid * 8;

    uint4 a0s0, a1s0, b0s0, b1s0, a0s1, a1s1, b0s1, b1s1;
    {   // kn=0: k9=0, cb=0, dd=-31
        a0s0 = *reinterpret_cast<const uint4*>(w2r + (size_t)(m0 + tcl) * 256 + tcid * 8);
        a1s0 = *reinterpret_cast<const uint4*>(w2r + (size_t)(m0 + 64 + tcl) * 256 + tcid * 8);
        b0s0 = *reinterpret_cast<const uint4*>(in2p + (size_t)(cellc[0] - 31) * 256 + tcid * 8);
        b1s0 = *reinterpret_cast<const uint4*>(in2p + (size_t)(cellc[1] - 31) * 256 + tcid * 8);
    }
    {   // kn=1: k9=0, cb=1, dd=-31
        const unsigned short* wb = w2r + 32;
        a0s1 = *reinterpret_cast<const uint4*>(wb + (size_t)(m0 + tcl) * 256 + tcid * 8);
        a1s1 = *reinterpret_cast<const uint4*>(wb + (size_t)(m0 + 64 + tcl) * 256 + tcid * 8);
        const unsigned short* bb = in2p + 32 + tcid * 8;
        b0s1 = *reinterpret_cast<const uint4*>(bb + (size_t)(cellc[0] - 31) * 256);
        b1s1 = *reinterpret_cast<const uint4*>(bb + (size_t)(cellc[1] - 31) * 256);
    }

    for (int kk = 0; kk < 72; kk += 2) {
        {   // even step: slot0, LDS buf 0
            unsigned short* A = As[0];
            unsigned short* B = Bs[0];
            *reinterpret_cast<uint4*>(A + wo) = a0s0;
            *reinterpret_cast<uint4*>(A + 64 * LDK1 + wo) = a1s0;
            *reinterpret_cast<uint4*>(B + wo) = b0s0;
            *reinterpret_cast<uint4*>(B + 64 * LDK1 + wo) = b1s0;
            if (kk < 70) {
                int kn = kk + 2;
                int k9 = kn >> 3, cb = kn & 7;
                int kh = k9 / 3, kw = k9 - 3 * kh;
                int dd = (kh - 1) * 30 + (kw - 1);
                const unsigned short* wb = w2r + (size_t)k9 * 65536 + cb * 32;
                a0s0 = *reinterpret_cast<const uint4*>(wb + (size_t)(m0 + tcl) * 256 + tcid * 8);
                a1s0 = *reinterpret_cast<const uint4*>(wb + (size_t)(m0 + 64 + tcl) * 256 + tcid * 8);
                const unsigned short* bb = in2p + (size_t)cb * 32 + tcid * 8;
                b0s0 = *reinterpret_cast<const uint4*>(bb + (size_t)(cellc[0] + dd) * 256);
                b1s0 = *reinterpret_cast<const uint4*>(bb + (size_t)(cellc[1] + dd) * 256);
            }
            lgkm_barrier();
            mfma_step(A, B, aoff, boff, LDK1, acc);
        }
        {   // odd step: slot1, LDS buf 1
            unsigned short* A = As[1];
            unsigned short* B = Bs[1];
            *reinterpret_cast<uint4*>(A + wo) = a0s1;
            *reinterpret_cast<uint4*>(A + 64 * LDK1 + wo) = a1s1;
            *reinterpret_cast<uint4*>(B + wo) = b0s1;
            *reinterpret_cast<uint4*>(B + 64 * LDK1 + wo) = b1s1;
            if (kk < 70) {
                int kn = kk + 3;
                int k9 = kn >> 3, cb = kn & 7;
                int kh = k9 / 3, kw = k9 - 3 * kh;
                int dd = (kh - 1) * 30 + (kw - 1);
                const unsigned short* wb = w2r + (size_t)k9 * 65536 + cb * 32;
                a0s1 = *reinterpret_cast<const uint4*>(wb + (size_t)(m0 + tcl) * 256 + tcid * 8);
                a1s1 = *reinterpret_cast<const uint4*>(wb + (size_t)(m0 + 64 + tcl) * 256 + tcid * 8);
                const unsigned short* bb = in2p + (size_t)cb * 32 + tcid * 8;
                b0s1 = *reinterpret_cast<const uint4*>(bb + (size_t)(cellc[0] + dd) * 256);
                b1s1 = *reinterpret_cast<const uint4*>(bb + (size_t)(cellc[1] + dd) * 256);
            }
            lgkm_barrier();
            mfma_step(A, B, aoff, boff, LDK1, acc);
        }
    }

    // epilogue: bias + relu -> bf16, flat [f][256]
#pragma unroll
    for (int j = 0; j < 4; ++j) {
        int f = f0 + wc * 64 + j * 16 + l15;
        unsigned short* dst = in3 + (size_t)f * 256;
#pragma unroll
        for (int i = 0; i < 4; ++i) {
            int co = m0 + wr * 64 + i * 16 + quad * 4;
            float4 bia = *reinterpret_cast<const float4*>(bias2 + co);
            f32x4 v = acc[i][j];
            ushort4 o;
            o.x = f2b(fmaxf(v.x + bia.x, 0.f));
            o.y = f2b(fmaxf(v.y + bia.y, 0.f));
            o.z = f2b(fmaxf(v.z + bia.z, 0.f));
            o.w = f2b(fmaxf(v.w + bia.w, 0.f));
            *reinterpret_cast<ushort4*>(dst + co) = o;
        }
    }
}

// ---------------- conv3: 1x1 256->1024; residual folded into acc-init; fp32 out -----------
// R5 form (best measured): A = spatial, B = weights; acc init = x + bias3 (C-in);
// 1-deep reg staging keeps natural VGPR < 128 -> 4 waves/SIMD. grid (392, 8), 256 threads
__global__ __launch_bounds__(256) void conv3_kernel(const unsigned short* __restrict__ in3,
                                                    const unsigned short* __restrict__ w3b,
                                                    const float* __restrict__ bias3,
                                                    const float* __restrict__ x,
                                                    float* __restrict__ out) {
    __shared__ unsigned short As[2][TILE1];
    __shared__ unsigned short Bs[2][TILE1];
    const int tid = threadIdx.x;
    const int f0 = blockIdx.x * 128;
    const int m0 = blockIdx.y * 128;
    const int lane = tid & 63, wave = tid >> 6;
    const int wr = wave >> 1, wc = wave & 1;
    const int l15 = lane & 15, quad = lane >> 4;
    const int tcid = tid & 3, tcl = tid >> 2;

    const unsigned short* aptr = in3 + (size_t)(f0 + tcl) * 256 + tcid * 8;   // spatial -> As
    const unsigned short* bptr = w3b + (size_t)(m0 + tcl) * 256 + tcid * 8;   // weights -> Bs

    const int aoff = (wr * 64 + l15) * LDK1 + quad * 8;
    const int boff = (wc * 64 + l15) * LDK1 + quad * 8;
    const int wo = tcl * LDK1 + tcid * 8;

    // staging prologue (1-deep)
    uint4 ra0, ra1, rb0, rb1;
    ra0 = *reinterpret_cast<const uint4*>(aptr);
    ra1 = *reinterpret_cast<const uint4*>(aptr + 16384);
    rb0 = *reinterpret_cast<const uint4*>(bptr);
    rb1 = *reinterpret_cast<const uint4*>(bptr + 16384);

    // accumulator init = residual + bias (MFMA C-in carries it through the k-loop)
    f32x4 acc[4][4];
#pragma unroll
    for (int j = 0; j < 4; ++j) {
        int co = m0 + wc * 64 + j * 16 + l15;
        float b = bias3[co];
#pragma unroll
        for (int i = 0; i < 4; ++i) {
            int fb = f0 + wr * 64 + i * 16 + quad * 4;
            int n = fb / 784;
            int sp = fb - n * 784;
            float4 xr = *reinterpret_cast<const float4*>(x + ((size_t)n * 1024 + co) * 784 + sp);
            f32x4 a;
            a.x = xr.x + b;
            a.y = xr.y + b;
            a.z = xr.z + b;
            a.w = xr.w + b;
            acc[i][j] = a;
        }
    }

    for (int kk = 0; kk < 8; ++kk) {
        unsigned short* A = As[kk & 1];
        unsigned short* B = Bs[kk & 1];
        *reinterpret_cast<uint4*>(A + wo) = ra0;
        *reinterpret_cast<uint4*>(A + 64 * LDK1 + wo) = ra1;
        *reinterpret_cast<uint4*>(B + wo) = rb0;
        *reinterpret_cast<uint4*>(B + 64 * LDK1 + wo) = rb1;
        if (kk < 7) {
            int k0 = (kk + 1) * 32;
            ra0 = *reinterpret_cast<const uint4*>(aptr + k0);
            ra1 = *reinterpret_cast<const uint4*>(aptr + 16384 + k0);
            rb0 = *reinterpret_cast<const uint4*>(bptr + k0);
            rb1 = *reinterpret_cast<const uint4*>(bptr + 16384 + k0);
        }
        lgkm_barrier();
        mfma_step(A, B, aoff, boff, LDK1, acc);
    }

    // epilogue: pure relu + float4 store (residual+bias already inside acc)
#pragma unroll
    for (int j = 0; j < 4; ++j) {
        int co = m0 + wc * 64 + j * 16 + l15;
#pragma unroll
        for (int i = 0; i < 4; ++i) {
            int fb = f0 + wr * 64 + i * 16 + quad * 4;
            int n = fb / 784;
            int sp = fb - n * 784;
            size_t off = ((size_t)n * 1024 + co) * 784 + sp;
            f32x4 v = acc[i][j];
            float4 o;
            o.x = fmaxf(v.x, 0.f);
            o.y = fmaxf(v.y, 0.f);
            o.z = fmaxf(v.z, 0.f);
            o.w = fmaxf(v.w, 0.f);
            *reinterpret_cast<float4*>(out + off) = o;
        }
    }
}

// ---------------- launch ----------------

extern "C" void kernel_launch(void* const* d_in, const int* in_sizes, int n_in,
                              void* d_out, int out_size, void* d_ws, size_t ws_size,
                              hipStream_t stream) {
    const float* x  = (const float*)d_in[0];
    const float* w1 = (const float*)d_in[1];
    const float* w2 = (const float*)d_in[2];
    const float* w3 = (const float*)d_in[3];
    const float* g1 = (const float*)d_in[4];
    const float* b1 = (const float*)d_in[5];
    const float* m1 = (const float*)d_in[6];
    const float* v1 = (const float*)d_in[7];
    const float* g2 = (const float*)d_in[8];
    const float* b2 = (const float*)d_in[9];
    const float* m2 = (const float*)d_in[10];
    const float* v2 = (const float*)d_in[11];
    const float* g3 = (const float*)d_in[12];
    const float* b3 = (const float*)d_in[13];
    const float* m3 = (const float*)d_in[14];
    const float* v3 = (const float*)d_in[15];

    char* ws = (char*)d_ws;
    unsigned short* w1b  = (unsigned short*)(ws + 0);         //   524288 B
    unsigned short* w2r  = (unsigned short*)(ws + 524288);    //  1179648 B
    unsigned short* w3b  = (unsigned short*)(ws + 1703936);   //   524288 B
    float* bias1         = (float*)(ws + 2228224);            //     1024 B
    float* bias2         = (float*)(ws + 2229248);            //     1024 B
    float* bias3         = (float*)(ws + 2230272);            //     4096 B
    unsigned short* in2p = (unsigned short*)(ws + 2234368);   // 29491200 B (64*900*256 bf16)
    unsigned short* in3  = (unsigned short*)(ws + 31725568);  // 25690112 B (50176*256 bf16)
    // total: ~57.4 MB

    prep_all<<<5286, 256, 0, stream>>>(w1, w2, w3,
                                       g1, b1, m1, v1, g2, b2, m2, v2, g3, b3, m3, v3,
                                       w1b, w2r, w3b, bias1, bias2, bias3, in2p);

    conv1_kernel<<<dim3(392), 512, 0, stream>>>(x, w1b, bias1, in2p);
    conv2_kernel<<<dim3(392, 2), 256, 0, stream>>>(in2p, w2r, bias2, in3);
    conv3_kernel<<<dim3(392, 8), 256, 0, stream>>>(in3, w3b, bias3, x, (float*)d_out);
}